// Round 5
// baseline (9092.937 us; speedup 1.0000x reference)
//
#include <hip/hip_runtime.h>
#include <hip/hip_bf16.h>

typedef __attribute__((ext_vector_type(8))) short short8;
typedef __attribute__((ext_vector_type(4))) float f32x4;
typedef __attribute__((ext_vector_type(2))) float f32x2;
typedef unsigned short u16;
typedef unsigned int u32;

#define DEV __device__ __forceinline__

// ---- problem dims ----
static constexpr int Hd    = 256;
static constexpr int Bb    = 32;
static constexpr int Pp    = 400;
static constexpr int Qq    = 40;
static constexpr int NROWS = Pp * Bb + Qq * Bb;   // 14080
static constexpr int PROBE_MAGIC = 1234567;

// ---- numeric helpers ----
DEV float bf2f(u16 u) { u32 i = ((u32)u) << 16; float f; __builtin_memcpy(&f, &i, 4); return f; }
DEV u16 f2bf(float f) { u32 i; __builtin_memcpy(&i, &f, 4); i += 0x7FFFu + ((i >> 16) & 1u); return (u16)(i >> 16); }
DEV float sigf(float x) { return __builtin_amdgcn_rcpf(1.f + __expf(-x)); }
DEV float tanhf_(float x) {
  float ax = __builtin_fabsf(x);
  float t = __expf(2.f * ax);
  float r = 1.f - 2.f * __builtin_amdgcn_rcpf(t + 1.f);
  return x < 0.f ? -r : r;
}
DEV f32x4 mfma32(short8 a, short8 b, f32x4 c) {
  return __builtin_amdgcn_mfma_f32_16x16x32_bf16(a, b, c, 0, 0, 0);
}
DEV short8 zero8() { short8 z = {0,0,0,0,0,0,0,0}; return z; }

struct KArgs {
  const int *pids, *qids, *plen, *qlen;
  const float *embedF, *preWihF, *preWhhF, *preBF, *WqF, *WpF, *bpF, *WhF,
              *walphaF, *balphaF, *mWihF, *mWhhF, *mBF, *WmF, *WaF, *baF,
              *wbetaF, *bbetaF, *pWihF, *pWhhF, *pBF;
  int* bar;   // [0..511] barrier slots; [768..783] probes
  u16 *WqT, *WpT, *WmT, *WihP, *Xpad, *preX, *Hp, *Hq, *Hrb, *wq, *wHr, *haB,
      *attQb, *pWihB, *pWhhB;
  float *hpWp, *attM, *pe, *scores, *aWa, *gatesW;
  float* out;   // FLOAT32 output (reference returns float32)
};

DEV void probe_mark(int* bar, int idx) {
  if (blockIdx.x == 0 && threadIdx.x == 0)
    __hip_atomic_store(bar + 768 + idx, PROBE_MAGIC, __ATOMIC_RELEASE, __HIP_MEMORY_SCOPE_AGENT);
}

// ---- group barrier among n blocks (agent scope, monotone gen sense) ----
DEV void barn(int* base, int grp, int n, int gen) {
  __syncthreads();
  if (threadIdx.x == 0) {
    int* c = base + grp * 128;
    int* g = base + grp * 128 + 64;
    if (__hip_atomic_fetch_add(c, 1, __ATOMIC_ACQ_REL, __HIP_MEMORY_SCOPE_AGENT) == n - 1) {
      __hip_atomic_store(c, 0, __ATOMIC_RELAXED, __HIP_MEMORY_SCOPE_AGENT);
      __hip_atomic_store(g, gen, __ATOMIC_RELEASE, __HIP_MEMORY_SCOPE_AGENT);
    } else {
      while (__hip_atomic_load(g, __ATOMIC_ACQUIRE, __HIP_MEMORY_SCOPE_AGENT) < gen) {}
    }
  }
  __syncthreads();
}

// ======================= k_prep: conversions / gather / pad =======================
__global__ __launch_bounds__(256) void k_prep(KArgs A) {
  const int gtid = blockIdx.x * 256 + threadIdx.x;
  const int GS = 256 * 256;
  for (int idx = gtid; idx < 1024 * 160; idx += GS) {
    int row = idx / 160, cd = idx - row * 160;
    u32 v = 0;
    if (cd < 150) {
      f32x2 e2 = *(const f32x2*)(A.preWihF + (size_t)row * 300 + cd * 2);
      v = (u32)f2bf(e2[0]) | ((u32)f2bf(e2[1]) << 16);
    }
    *(u32*)(A.WihP + (size_t)row * 320 + cd * 2) = v;
  }
  for (int idx = gtid; idx < NROWS * 160; idx += GS) {
    int row = idx / 160, cd = idx - row * 160;
    int id = (row < Pp * Bb) ? A.pids[row] : A.qids[row - Pp * Bb];
    u32 v = 0;
    if (cd < 150) {
      f32x2 e2 = *(const f32x2*)(A.embedF + (size_t)id * 300 + cd * 2);
      v = (u32)f2bf(e2[0]) | ((u32)f2bf(e2[1]) << 16);
    }
    *(u32*)(A.Xpad + (size_t)row * 320 + cd * 2) = v;
  }
  for (int idx = gtid; idx < 65536; idx += GS) {
    int r = idx >> 8, c = idx & 255;
    A.WqT[idx] = f2bf(A.WqF[c * 256 + r]);
    A.WpT[idx] = f2bf(A.WpF[c * 256 + r]);
  }
  for (int idx = gtid; idx < 131072; idx += GS) {
    int r = idx >> 9, c = idx & 511;
    A.WmT[idx] = f2bf(A.WmF[c * 256 + r]);
  }
  for (int idx = gtid; idx < 524288 + 262144; idx += GS) {
    if (idx < 524288) A.pWihB[idx] = f2bf(A.pWihF[idx]);
    else              A.pWhhB[idx - 524288] = f2bf(A.pWhhF[idx - 524288]);
  }
  if (gtid < 32 * 256) {           // pointer-net init: aWa = ba (ha=0), haB = 0
    A.aWa[gtid] = A.baF[gtid & 255];
    A.haB[gtid] = 0;
  }
  probe_mark(A.bar, 0);
}

// ======================= k_gemm: generic MFMA GEMM =======================
// A[M,K] bf16 row-major, B[N,K] bf16 row-major (B^T input); M=Mt64*64, N=Nt64*64, K=nk*32
struct GemmArgs { const u16* Ag; int lda; const u16* Bg; int ldb; int Mt64, Nt64, nk; float* Cf; u16* Cb; int ldc; int* bar; int probe; };

__global__ __launch_bounds__(512) void k_gemm(GemmArgs g) {
  const int tid = threadIdx.x, lane = tid & 63;
  const int r16 = lane & 15, kl = (lane >> 4) * 8;
  const int ntile = g.Mt64 * g.Nt64;
  const int stride = gridDim.x * 8;
  for (int tix = blockIdx.x * 8 + (tid >> 6); tix < ntile; tix += stride) {
    int m0 = (tix / g.Nt64) * 64, n0 = (tix % g.Nt64) * 64;
    f32x4 acc[4][4] = {};
    for (int kb = 0; kb < g.nk; ++kb) {
      int k0 = kb * 32 + kl;
      short8 a[4], b[4];
#pragma unroll
      for (int i = 0; i < 4; ++i) {
        a[i] = *(const short8*)(g.Ag + (size_t)(m0 + i * 16 + r16) * g.lda + k0);
        b[i] = *(const short8*)(g.Bg + (size_t)(n0 + i * 16 + r16) * g.ldb + k0);
      }
#pragma unroll
      for (int mi = 0; mi < 4; ++mi)
#pragma unroll
        for (int ni = 0; ni < 4; ++ni) acc[mi][ni] = mfma32(a[mi], b[ni], acc[mi][ni]);
    }
#pragma unroll
    for (int mi = 0; mi < 4; ++mi)
#pragma unroll
      for (int ni = 0; ni < 4; ++ni)
#pragma unroll
        for (int j = 0; j < 4; ++j) {
          int r = m0 + mi * 16 + (lane >> 4) * 4 + j, cc = n0 + ni * 16 + r16;
          if (g.Cf) g.Cf[(size_t)r * g.ldc + cc] = acc[mi][ni][j];
          else      g.Cb[(size_t)r * g.ldc + cc] = f2bf(acc[mi][ni][j]);
        }
  }
  probe_mark(g.bar, g.probe);
}

// ======================= k_prescan: preprocess LSTM (h := tanh(c)*m) =======================
// 32 blocks: 0-15 passage (grp0), 16-31 question (grp1); block gi owns hidden [gi*16, gi*16+16)
__global__ __launch_bounds__(512) void k_prescan(KArgs A) {
  __shared__ __align__(16) unsigned char sm[33280];
  float* PRE = (float*)(sm + 24576);     // [32][48]
  float* CL  = (float*)(sm + 30720);     // [32][16]
  float* PBL = (float*)(sm + 32768);     // [48]
  const int blk = blockIdx.x;
  const int gi  = blk & 15;
  const int grp = blk >> 4;
  const int steps  = grp ? Qq : Pp;
  const int* lens  = grp ? A.qlen : A.plen;
  u16* Hs          = grp ? A.Hq : A.Hp;
  const int xoff   = grp ? Pp * Bb : 0;

  const int tid = threadIdx.x, lane = tid & 63, wv = tid >> 6;
  const int r16 = lane & 15, kl = (lane >> 4) * 8;
  const int h0 = gi * 16;

  for (int idx = tid; idx < 48 * 256; idx += 512) {
    int row = idx >> 8, k = idx & 255;
    int gate = (row >> 4) * 256 + h0 + (row & 15);
    int byte = row * 512 + ((2 * k) ^ ((row & 7) << 4));
    *(u16*)(sm + byte) = f2bf(A.preWhhF[(size_t)gate * 256 + k]);
  }
  for (int idx = tid; idx < 32 * 16; idx += 512) CL[idx] = 0.f;
  if (tid < 48) PBL[tid] = A.preBF[(tid >> 4) * 256 + h0 + (tid & 15)];
  __syncthreads();

  int gen = 0;
#pragma unroll 1
  for (int t = 0; t < steps; ++t) {
    if (wv < 6) {
      int mi = wv & 1, ni = wv >> 1;
      int chain = mi * 16 + r16;
      f32x4 acc = {0.f, 0.f, 0.f, 0.f};
#pragma unroll
      for (int kb = 0; kb < 8; ++kb) {
        int k0 = kb * 32 + kl;
        short8 a = zero8();
        if (t > 0) a = *(const short8*)(Hs + (size_t)((t - 1) * 32 + chain) * 256 + k0);
        int row = ni * 16 + r16;
        short8 b = *(const short8*)(sm + row * 512 + ((2 * k0) ^ ((row & 7) << 4)));
        acc = mfma32(a, b, acc);
      }
      int col = ni * 16 + r16;
#pragma unroll
      for (int j = 0; j < 4; ++j)
        PRE[(mi * 16 + (lane >> 4) * 4 + j) * 48 + col] = acc[j];
    }
    __syncthreads();
    {
      int chain = tid >> 4, hd = tid & 15;
      size_t xr = (size_t)(xoff + t * 32 + chain) * 1024;
      float ip = PRE[chain * 48 + hd]      + bf2f(A.preX[xr + h0 + hd])       + PBL[hd];
      float fp = PRE[chain * 48 + 16 + hd] + bf2f(A.preX[xr + 256 + h0 + hd]) + PBL[16 + hd];
      float gp = PRE[chain * 48 + 32 + hd] + bf2f(A.preX[xr + 512 + h0 + hd]) + PBL[32 + hd];
      float c2 = sigf(fp) * CL[chain * 16 + hd] + sigf(ip) * tanhf_(gp);
      float mt = (t < lens[chain]) ? 1.f : 0.f;
      float h2 = tanhf_(c2) * mt;
      c2 *= mt;
      CL[chain * 16 + hd] = c2;
      Hs[(size_t)(t * 32 + chain) * 256 + h0 + hd] = f2bf(h2);
    }
    barn(A.bar, grp, 16, ++gen);
  }
  probe_mark(A.bar, 2);
}

// ======================= k_match: match-LSTM, both directions =======================
// 32 blocks: 0-15 fwd (grp2), 16-31 bwd (grp3); block gi owns hidden [gi*16, gi*16+16)
__global__ __launch_bounds__(512) void k_match(KArgs A) {
  __shared__ __align__(16) unsigned char sm[122880];
  u16*   WHT = (u16*)(sm + 98304);        // [256][16]  Wh^T slice
  float* PRE = (float*)(sm + 106496);     // [32][64]
  float* CL  = (float*)(sm + 114688);     // [32][16]
  float* EL  = (float*)(sm + 116736);     // [2][256]
  u16*   H2L = (u16*)(sm + 118784);       // [32][16]
  float* SL  = (float*)(sm + 119808);     // [2][40]
  float* AL  = (float*)(sm + 120128);     // [2][40]
  float* BPL = (float*)(sm + 120448);     // [256]
  float* WAL = (float*)(sm + 121472);     // [256]
  float* MBL = (float*)(sm + 122496);     // [64]

  const int blk = blockIdx.x;
  const int gi  = blk & 15;
  const int dir = blk >> 4;
  const int grp = 2 + dir;
  const int tid = threadIdx.x, lane = tid & 63, wv = tid >> 6;
  const int r16 = lane & 15, kl = (lane >> 4) * 8;
  const int h0 = gi * 16;
  float* peBlk = A.pe + (size_t)((dir * 16 + gi) * 32) * 256;

  for (int idx = tid; idx < 64 * 768; idx += 512) {
    int row = idx / 768, k = idx - row * 768;
    int gate = (row >> 4) * 256 + h0 + (row & 15);
    float v = (k < 512) ? A.mWihF[(size_t)gate * 512 + k] : A.mWhhF[(size_t)gate * 256 + (k - 512)];
    int byte = row * 1536 + ((2 * k) ^ ((row & 7) << 4));
    *(u16*)(sm + byte) = f2bf(v);
  }
  for (int idx = tid; idx < 256 * 16; idx += 512) {
    int h = idx >> 4, jj = idx & 15;
    WHT[h * 16 + jj] = f2bf(A.WhF[(size_t)(h0 + jj) * 256 + h]);
  }
  for (int idx = tid; idx < 32 * 16; idx += 512) CL[idx] = 0.f;
  for (int idx = tid; idx < 32 * 256; idx += 512) peBlk[idx] = 0.f;
  if (tid < 256) { BPL[tid] = A.bpF[tid]; WAL[tid] = A.walphaF[tid]; }
  if (tid < 64) MBL[tid] = A.mBF[(tid >> 4) * 256 + h0 + (tid & 15)];
  __syncthreads();

  const float bAl = A.balphaF[0];
  int gen = 0;
#pragma unroll 1
  for (int t = 0; t < Pp; ++t) {
    int p  = dir ? (Pp - 1 - t) : t;
    int pp = dir ? (p + 1) : (p - 1);
    barn(A.bar, grp, 16, ++gen);            // h_{t-1} + partial-e ready (and init at t=0)

    // ---- e = sum of 16 partials, for this block's 2 chains ----
    {
      int c = tid >> 8, h = tid & 255;
      int b = gi * 2 + c;
      const float* pc = A.pe + (size_t)(dir * 16 * 32 + b) * 256 + h;
      float e = 0.f;
#pragma unroll
      for (int g = 0; g < 16; ++g) e += pc[(size_t)g * 32 * 256];
      EL[c * 256 + h] = e;
    }
    __syncthreads();
    // ---- attention scores ----
    {
      int c = wv >> 2;
      int b = gi * 2 + c;
      float base[4];
#pragma unroll
      for (int j = 0; j < 4; ++j) {
        int h = lane + 64 * j;
        base[j] = A.hpWp[(size_t)(p * 32 + b) * 256 + h] + BPL[h] + EL[c * 256 + h];
      }
      int q4 = wv & 3;
#pragma unroll
      for (int i = 0; i < 10; ++i) {
        int q = q4 + 4 * i;
        float s = 0.f;
#pragma unroll
        for (int j = 0; j < 4; ++j) {
          int h = lane + 64 * j;
          s += WAL[h] * tanhf_(bf2f(A.attQb[(size_t)(q * 32 + b) * 256 + h]) + base[j]);
        }
#pragma unroll
        for (int off = 32; off; off >>= 1) s += __shfl_xor(s, off, 64);
        if (lane == 0) SL[c * 40 + q] = s;
      }
    }
    __syncthreads();
    // ---- softmax over q ----
    if ((wv & 3) == 0) {
      int c = wv >> 2;
      float x = (lane < 40) ? (SL[c * 40 + lane] + bAl) : -3.4e38f;
      float m = x;
#pragma unroll
      for (int off = 32; off; off >>= 1) m = fmaxf(m, __shfl_xor(m, off, 64));
      float e = (lane < 40) ? __expf(x - m) : 0.f;
      float su = e;
#pragma unroll
      for (int off = 32; off; off >>= 1) su += __shfl_xor(su, off, 64);
      if (lane < 40) AL[c * 40 + lane] = e / su;
    }
    __syncthreads();
    // ---- wq = sum_q alpha * Hq, masked, bf16 ----
    {
      int c = tid >> 8, h = tid & 255;
      int b = gi * 2 + c;
      float acc = 0.f;
#pragma unroll 8
      for (int q = 0; q < 40; ++q) acc += AL[c * 40 + q] * bf2f(A.Hq[(size_t)(q * 32 + b) * 256 + h]);
      float mt = (p < A.plen[b]) ? 1.f : 0.f;
      A.wq[(size_t)(dir * 32 + b) * 256 + h] = f2bf(acc * mt);
    }
    barn(A.bar, grp, 16, ++gen);            // wq ready (all chains)

    // ---- gates GEMM: [32,768] @ Wslice^T -> [32,64] ----
    {
      int mi = wv >> 2, ni = wv & 3;
      int chain = mi * 16 + r16;
      f32x4 acc = {0.f, 0.f, 0.f, 0.f};
#pragma unroll
      for (int kb = 0; kb < 24; ++kb) {
        int k0 = kb * 32 + kl;
        short8 a;
        if (kb < 8)       a = *(const short8*)(A.Hp + (size_t)(p * 32 + chain) * 256 + k0);
        else if (kb < 16) a = *(const short8*)(A.wq + (size_t)(dir * 32 + chain) * 256 + (k0 - 256));
        else {
          if (t == 0) a = zero8();
          else        a = *(const short8*)(A.Hrb + (size_t)(pp * 32 + chain) * 512 + dir * 256 + (k0 - 512));
        }
        int row = ni * 16 + r16;
        short8 b = *(const short8*)(sm + row * 1536 + ((2 * k0) ^ ((row & 7) << 4)));
        acc = mfma32(a, b, acc);
      }
      int col = ni * 16 + r16;
#pragma unroll
      for (int j = 0; j < 4; ++j)
        PRE[(mi * 16 + (lane >> 4) * 4 + j) * 64 + col] = acc[j];
    }
    __syncthreads();
    // ---- cell elementwise ----
    {
      int chain = tid >> 4, hd = tid & 15;
      float ig = PRE[chain * 64 + hd]      + MBL[hd];
      float fg = PRE[chain * 64 + 16 + hd] + MBL[16 + hd];
      float gg = PRE[chain * 64 + 32 + hd] + MBL[32 + hd];
      float og = PRE[chain * 64 + 48 + hd] + MBL[48 + hd];
      float c2 = sigf(fg) * CL[chain * 16 + hd] + sigf(ig) * tanhf_(gg);
      float h2 = sigf(og) * tanhf_(c2);
      float mt = (p < A.plen[chain]) ? 1.f : 0.f;
      c2 *= mt; h2 *= mt;
      CL[chain * 16 + hd] = c2;
      u16 hb = f2bf(h2);
      H2L[chain * 16 + hd] = hb;
      A.Hrb[(size_t)(p * 32 + chain) * 512 + dir * 256 + h0 + hd] = hb;
    }
    __syncthreads();
    // ---- partial e for next step: pe = h2_slice @ Wh[slice,:] (K=16 pad 32) ----
    {
#pragma unroll
      for (int i = 0; i < 4; ++i) {
        int task = wv * 4 + i;
        int nf = task & 15, mi = task >> 4;
        int chain = mi * 16 + r16;
        int hcol = nf * 16 + r16;
        short8 a = zero8(), b = zero8();
        if (kl < 16) {
          a = *(const short8*)(H2L + chain * 16 + kl);
          b = *(const short8*)(WHT + hcol * 16 + kl);
        }
        f32x4 acc = {0.f, 0.f, 0.f, 0.f};
        acc = mfma32(a, b, acc);
#pragma unroll
        for (int j = 0; j < 4; ++j)
          peBlk[(size_t)(mi * 16 + (lane >> 4) * 4 + j) * 256 + hcol] = acc[j];
      }
    }
  }
  probe_mark(A.bar, 5);
}

// ======================= pointer net =======================
__global__ __launch_bounds__(512) void k_scores(KArgs A, int probe) {
  const int blk = blockIdx.x, tid = threadIdx.x, lane = tid & 63, wv = tid >> 6;
  for (int j = wv; j < 50; j += 8) {
    int id = blk * 50 + j;
    int p = id >> 5, b = id & 31;
    float s = 0.f;
#pragma unroll
    for (int jj = 0; jj < 4; ++jj) {
      int h = lane + 64 * jj;
      s += A.wbetaF[h] * tanhf_(A.attM[(size_t)(p * 32 + b) * 256 + h] + A.aWa[b * 256 + h]);
    }
#pragma unroll
    for (int off = 32; off; off >>= 1) s += __shfl_xor(s, off, 64);
    if (lane == 0)
      A.scores[p * 32 + b] = (p < A.plen[b]) ? (s + A.bbetaF[0]) : -1e30f;
  }
  probe_mark(A.bar, probe);
}

__global__ __launch_bounds__(512) void k_soft(KArgs A, int k, int probe) {
  __shared__ __align__(16) unsigned char sm[2048];
  float* BL = (float*)sm;            // [400]
  float* RED = (float*)(sm + 1664);  // [16]
  const int b = blockIdx.x, tid = threadIdx.x, lane = tid & 63, wv = tid >> 6;
  float x = (tid < 400) ? A.scores[tid * 32 + b] : -3.4e38f;
  float m = x;
#pragma unroll
  for (int off = 32; off; off >>= 1) m = fmaxf(m, __shfl_xor(m, off, 64));
  if (lane == 0) RED[wv] = m;
  __syncthreads();
  if (tid == 0) {
    float mm = RED[0];
#pragma unroll
    for (int i = 1; i < 8; ++i) mm = fmaxf(mm, RED[i]);
    RED[0] = mm;
  }
  __syncthreads();
  float M = RED[0];
  float e = (tid < 400) ? __expf(x - M) : 0.f;
  float su = e;
#pragma unroll
  for (int off = 32; off; off >>= 1) su += __shfl_xor(su, off, 64);
  if (lane == 0) RED[8 + wv] = su;
  __syncthreads();
  if (tid == 0) {
    float ss = 0.f;
#pragma unroll
    for (int i = 0; i < 8; ++i) ss += RED[8 + i];
    RED[8] = ss;
  }
  __syncthreads();
  float SUM = RED[8];
  if (tid < 400) {
    float beta = (e / SUM) * ((tid < A.plen[b]) ? 1.f : 0.f);
    A.out[(size_t)(k * 32 + b) * 400 + tid] = beta;   // FLOAT32 output
    BL[tid] = beta;
  }
  if (k == 0) {
    __syncthreads();
    float acc = 0.f;
#pragma unroll 4
    for (int p = 0; p < 400; ++p) acc += BL[p] * bf2f(A.Hrb[(size_t)(p * 32 + b) * 512 + tid]);
    A.wHr[b * 512 + tid] = f2bf(acc);
  }
  probe_mark(A.bar, probe);
}

__global__ __launch_bounds__(128) void k_pgates(KArgs A) {
  const int blk = blockIdx.x, tid = threadIdx.x, lane = tid & 63, wv = tid >> 6;
  const int r16 = lane & 15, kl = (lane >> 4) * 8;
  const int g0 = blk * 16;
  const int mi = wv, chain = mi * 16 + r16;
  f32x4 acc = {0.f, 0.f, 0.f, 0.f};
#pragma unroll
  for (int kb = 0; kb < 24; ++kb) {
    int k0 = kb * 32 + kl;
    short8 a, b;
    if (kb < 16) {
      a = *(const short8*)(A.wHr + (size_t)chain * 512 + k0);
      b = *(const short8*)(A.pWihB + (size_t)(g0 + r16) * 512 + k0);
    } else {
      a = *(const short8*)(A.haB + (size_t)chain * 256 + (k0 - 512));
      b = *(const short8*)(A.pWhhB + (size_t)(g0 + r16) * 256 + (k0 - 512));
    }
    acc = mfma32(a, b, acc);
  }
#pragma unroll
  for (int j = 0; j < 4; ++j)
    A.gatesW[(size_t)(mi * 16 + (lane >> 4) * 4 + j) * 1024 + g0 + r16] = acc[j];
  probe_mark(A.bar, 9);
}

__global__ __launch_bounds__(256) void k_pcell(KArgs A) {
  __shared__ float HL[256];
  const int b = blockIdx.x, hd = threadIdx.x;
  {
    float ig = A.gatesW[(size_t)b * 1024 + hd]       + A.pBF[hd];
    float gg = A.gatesW[(size_t)b * 1024 + 512 + hd] + A.pBF[512 + hd];
    float og = A.gatesW[(size_t)b * 1024 + 768 + hd] + A.pBF[768 + hd];
    float c2 = sigf(ig) * tanhf_(gg);      // c_prev = 0
    float h2 = sigf(og) * tanhf_(c2);
    HL[hd] = h2;
    A.haB[b * 256 + hd] = f2bf(h2);
  }
  __syncthreads();
  {
    float acc = A.baF[hd];
#pragma unroll 8
    for (int kk = 0; kk < 256; ++kk) acc += HL[kk] * A.WaF[(size_t)kk * 256 + hd];
    A.aWa[b * 256 + hd] = acc;
  }
  probe_mark(A.bar, 10);
}

// ======================= k_diag: probe check -> sentinel into out =======================
// If probe i (0..12) is the first missing one, writes 128*2^i to out[0..7] (f32).
__global__ __launch_bounds__(64) void k_diag(KArgs A) {
  if (threadIdx.x == 0 && blockIdx.x == 0) {
    int bad = -1;
    for (int i = 0; i < 13; ++i) {
      int v = __hip_atomic_load(A.bar + 768 + i, __ATOMIC_ACQUIRE, __HIP_MEMORY_SCOPE_AGENT);
      if (v != PROBE_MAGIC) { bad = i; break; }
    }
    if (bad >= 0) {
      float s = 128.f * (float)(1 << bad);
      for (int j = 0; j < 8; ++j) A.out[j] = s;
    }
  }
}

extern "C" void kernel_launch(void* const* d_in, const int* in_sizes, int n_in,
                              void* d_out, int out_size, void* d_ws, size_t ws_size,
                              hipStream_t stream) {
  (void)in_sizes; (void)n_in; (void)ws_size;
  KArgs A;
  A.pids = (const int*)d_in[0];
  A.qids = (const int*)d_in[1];
  A.plen = (const int*)d_in[2];
  A.qlen = (const int*)d_in[3];
  // d_in[4] = answer (unused by forward)
  A.embedF  = (const float*)d_in[5];
  A.preWihF = (const float*)d_in[6];
  A.preWhhF = (const float*)d_in[7];
  A.preBF   = (const float*)d_in[8];
  A.WqF     = (const float*)d_in[9];
  A.WpF     = (const float*)d_in[10];
  A.bpF     = (const float*)d_in[11];
  A.WhF     = (const float*)d_in[12];
  A.walphaF = (const float*)d_in[13];
  A.balphaF = (const float*)d_in[14];
  A.mWihF   = (const float*)d_in[15];
  A.mWhhF   = (const float*)d_in[16];
  A.mBF     = (const float*)d_in[17];
  A.WmF     = (const float*)d_in[18];
  A.WaF     = (const float*)d_in[19];
  A.baF     = (const float*)d_in[20];
  A.wbetaF  = (const float*)d_in[21];
  A.bbetaF  = (const float*)d_in[22];
  A.pWihF   = (const float*)d_in[23];
  A.pWhhF   = (const float*)d_in[24];
  A.pBF     = (const float*)d_in[25];

  char* w = (char*)d_ws;
  size_t off = 0;
  auto take = [&](size_t bytes) { void* p = w + off; off += (bytes + 255) & ~(size_t)255; return p; };
  A.bar    = (int*)take(4096);
  A.WqT    = (u16*)take(256 * 256 * 2);
  A.WpT    = (u16*)take(256 * 256 * 2);
  A.WmT    = (u16*)take(256 * 512 * 2);
  A.WihP   = (u16*)take((size_t)1024 * 320 * 2);
  A.Xpad   = (u16*)take((size_t)NROWS * 320 * 2);
  A.preX   = (u16*)take((size_t)NROWS * 1024 * 2);
  A.Hp     = (u16*)take((size_t)Pp * Bb * 256 * 2);
  A.Hq     = (u16*)take((size_t)Qq * Bb * 256 * 2);
  A.Hrb    = (u16*)take((size_t)Pp * Bb * 512 * 2);
  A.wq     = (u16*)take(2 * 32 * 256 * 2);
  A.wHr    = (u16*)take(32 * 512 * 2);
  A.haB    = (u16*)take(32 * 256 * 2);
  A.attQb  = (u16*)take((size_t)Qq * Bb * 256 * 2);
  A.pWihB  = (u16*)take((size_t)1024 * 512 * 2);
  A.pWhhB  = (u16*)take((size_t)1024 * 256 * 2);
  A.hpWp   = (float*)take((size_t)Pp * Bb * 256 * 4);
  A.attM   = (float*)take((size_t)Pp * Bb * 256 * 4);
  A.pe     = (float*)take((size_t)2 * 16 * 32 * 256 * 4);
  A.scores = (float*)take((size_t)Pp * Bb * 4);
  A.aWa    = (float*)take(32 * 256 * 4);
  A.gatesW = (float*)take((size_t)32 * 1024 * 4);
  A.out    = (float*)d_out;

  // Host-alive sentinel: f32 0x3C3C3C3C ~= 0.0115 in out[0..15]; overwritten by k_soft on success.
  hipMemsetAsync(d_out, 0x3C, 64, stream);
  hipMemsetAsync(A.bar, 0, 4096, stream);   // barrier slots + probes

  (void)hipGetLastError();   // clear stale error state
  size_t outB = (size_t)out_size * 4;
  int li = 0;
  // On synchronous launch failure: fill out with byte 0x41+li -> absmax identifies launch index.
#define CK  if (hipGetLastError() != hipSuccess) { hipMemsetAsync(d_out, 0x41 + li, outB, stream); return; } ++li;

  hipLaunchKernelGGL(k_prep, dim3(256), dim3(256), 0, stream, A); CK;

  GemmArgs g1{A.Xpad, 320, A.WihP, 320, NROWS / 64, 16, 10, nullptr, A.preX, 1024, A.bar, 1};
  hipLaunchKernelGGL(k_gemm, dim3(256), dim3(512), 0, stream, g1); CK;

  hipLaunchKernelGGL(k_prescan, dim3(32), dim3(512), 0, stream, A); CK;

  GemmArgs g2{A.Hq, 256, A.WqT, 256, 20, 4, 8, nullptr, A.attQb, 256, A.bar, 3};
  hipLaunchKernelGGL(k_gemm, dim3(16), dim3(512), 0, stream, g2); CK;
  GemmArgs g3{A.Hp, 256, A.WpT, 256, 200, 4, 8, A.hpWp, nullptr, 256, A.bar, 4};
  hipLaunchKernelGGL(k_gemm, dim3(128), dim3(512), 0, stream, g3); CK;

  hipLaunchKernelGGL(k_match, dim3(32), dim3(512), 0, stream, A); CK;

  GemmArgs g4{A.Hrb, 512, A.WmT, 512, 200, 4, 16, A.attM, nullptr, 256, A.bar, 6};
  hipLaunchKernelGGL(k_gemm, dim3(128), dim3(512), 0, stream, g4); CK;

  hipLaunchKernelGGL(k_scores, dim3(256), dim3(512), 0, stream, A, 7); CK;
  hipLaunchKernelGGL(k_soft,   dim3(32),  dim3(512), 0, stream, A, 0, 8); CK;
  hipLaunchKernelGGL(k_pgates, dim3(64),  dim3(128), 0, stream, A); CK;
  hipLaunchKernelGGL(k_pcell,  dim3(32),  dim3(256), 0, stream, A); CK;
  hipLaunchKernelGGL(k_scores, dim3(256), dim3(512), 0, stream, A, 11); CK;
  hipLaunchKernelGGL(k_soft,   dim3(32),  dim3(512), 0, stream, A, 1, 12); CK;

  hipLaunchKernelGGL(k_diag,   dim3(1),   dim3(64),  0, stream, A); CK;
#undef CK
}